// Round 3
// baseline (274.354 us; speedup 1.0000x reference)
//
#include <hip/hip_runtime.h>
#include <hip/hip_bf16.h>
#include <math.h>

typedef __bf16 bf16_t;
typedef __bf16 bf16x8 __attribute__((ext_vector_type(8)));
typedef __bf16 bf16x4 __attribute__((ext_vector_type(4)));
typedef short short4v __attribute__((ext_vector_type(4)));
typedef float f32x4 __attribute__((ext_vector_type(4)));

__device__ __forceinline__ f32x4 mfma_k32(bf16x8 a, bf16x8 b, f32x4 c) {
    return __builtin_amdgcn_mfma_f32_16x16x32_bf16(a, b, c, 0, 0, 0);
}

// raw v_exp_f32 (exp2): avoid OCML guard code around exp2f
__device__ __forceinline__ float fast_exp2(float x) {
#if __has_builtin(__builtin_amdgcn_exp2f)
    return __builtin_amdgcn_exp2f(x);
#else
    float r;
    asm("v_exp_f32 %0, %1" : "=v"(r) : "v"(x));
    return r;
#endif
}

// async global->LDS, 16B/lane; LDS dest = wave-uniform base + lane*16
__device__ __forceinline__ void async16(const bf16_t* g, __bf16* l) {
    __builtin_amdgcn_global_load_lds(
        (const __attribute__((address_space(1))) void*)g,
        (__attribute__((address_space(3))) void*)l, 16, 0, 0);
}

// XOR-swizzle: 16B chunks within each 64-col group, keyed by row&7 (global-side)
__device__ __forceinline__ int swz_col(int col, int row) {
    return (col & ~63) | ((((col >> 3) & 7) ^ (row & 7)) << 3) | (col & 7);
}

// ---------------------------------------------------------------------------
// fp32 -> bf16 swizzled converts, x and W merged into one launch.
// ---------------------------------------------------------------------------
__global__ __launch_bounds__(256) void cvt_all(const float* __restrict__ q,
                                               const float* __restrict__ k,
                                               const float* __restrict__ v,
                                               const float* __restrict__ Wq,
                                               const float* __restrict__ Wk,
                                               const float* __restrict__ Wv,
                                               const float* __restrict__ Wo,
                                               bf16_t* __restrict__ qc,
                                               bf16_t* __restrict__ kc,
                                               bf16_t* __restrict__ vc,
                                               bf16_t* __restrict__ Wc) {
    const int bx = blockIdx.x;
    if (bx < 2048) {
        size_t i = ((size_t)bx * 256 + threadIdx.x) * 8;
        int row = (int)(i >> 9), col = (int)(i & 511);
        size_t di = (size_t)row * 512 + swz_col(col, row);
        float4 a0 = *(const float4*)(q + i), a1 = *(const float4*)(q + i + 4);
        float4 b0 = *(const float4*)(k + i), b1 = *(const float4*)(k + i + 4);
        float4 c0 = *(const float4*)(v + i), c1 = *(const float4*)(v + i + 4);
        bf16x8 qo, ko, vo;
        qo[0]=(__bf16)a0.x; qo[1]=(__bf16)a0.y; qo[2]=(__bf16)a0.z; qo[3]=(__bf16)a0.w;
        qo[4]=(__bf16)a1.x; qo[5]=(__bf16)a1.y; qo[6]=(__bf16)a1.z; qo[7]=(__bf16)a1.w;
        ko[0]=(__bf16)b0.x; ko[1]=(__bf16)b0.y; ko[2]=(__bf16)b0.z; ko[3]=(__bf16)b0.w;
        ko[4]=(__bf16)b1.x; ko[5]=(__bf16)b1.y; ko[6]=(__bf16)b1.z; ko[7]=(__bf16)b1.w;
        vo[0]=(__bf16)c0.x; vo[1]=(__bf16)c0.y; vo[2]=(__bf16)c0.z; vo[3]=(__bf16)c0.w;
        vo[4]=(__bf16)c1.x; vo[5]=(__bf16)c1.y; vo[6]=(__bf16)c1.z; vo[7]=(__bf16)c1.w;
        *(bf16x8*)(qc + di) = qo;
        *(bf16x8*)(kc + di) = ko;
        *(bf16x8*)(vc + di) = vo;
    } else {
        const int b2 = bx - 2048;
        const int m = b2 >> 7;                   // which W
        const float* src = m == 0 ? Wq : m == 1 ? Wk : m == 2 ? Wv : Wo;
        const float sc = (m == 0) ? 0.125f * 1.44269504088896f : 1.0f;
        size_t i = ((size_t)(b2 & 127) * 256 + threadIdx.x) * 8;
        int row = (int)(i >> 9), col = (int)(i & 511);
        float4 a0 = *(const float4*)(src + i), a1 = *(const float4*)(src + i + 4);
        bf16x8 o;
        o[0]=(__bf16)(a0.x*sc); o[1]=(__bf16)(a0.y*sc); o[2]=(__bf16)(a0.z*sc); o[3]=(__bf16)(a0.w*sc);
        o[4]=(__bf16)(a1.x*sc); o[5]=(__bf16)(a1.y*sc); o[6]=(__bf16)(a1.z*sc); o[7]=(__bf16)(a1.w*sc);
        *(bf16x8*)(Wc + (size_t)m * 262144 + (size_t)row * 512 + swz_col(col, row)) = o;
    }
}

// ---------------------------------------------------------------------------
// 128x128-tile NT GEMM (m97 structure) — unchanged (control).
// ---------------------------------------------------------------------------
template<int MODE>
__device__ __forceinline__ void gemm128_body(const bf16_t* __restrict__ A,
                                             const bf16_t* __restrict__ B,
                                             void* __restrict__ outp,
                                             int m0, int n0) {
    __shared__ __bf16 Asm[128 * 64];
    __shared__ __bf16 Bsm[128 * 64];
    const int tid  = threadIdx.x;
    const int wave = tid >> 6;
    const int lane = tid & 63;
    const int quad = lane >> 4;
    const int l16  = lane & 15;
    const int swz  = l16 & 7;
    const int r8 = lane >> 3;
    const int c8 = (lane & 7) * 8;
    const int mrow0 = (wave & 1) * 64;
    const int ncol0 = (wave >> 1) * 64;

    f32x4 acc[4][4];
    for (int i = 0; i < 4; ++i)
        for (int j = 0; j < 4; ++j) acc[i][j] = (f32x4){0.f, 0.f, 0.f, 0.f};

    for (int kt = 0; kt < 512; kt += 64) {
        __syncthreads();
        for (int j = 0; j < 4; ++j) {
            async16(A + (size_t)(m0 + wave * 32 + j * 8 + r8) * 512 + kt + c8,
                    &Asm[(wave * 32 + j * 8) * 64]);
            async16(B + (size_t)(n0 + wave * 32 + j * 8 + r8) * 512 + kt + c8,
                    &Bsm[(wave * 32 + j * 8) * 64]);
        }
        __syncthreads();

        for (int ks = 0; ks < 2; ++ks) {
            bf16x8 af[4];
            for (int mt = 0; mt < 4; ++mt)
                af[mt] = *(const bf16x8*)&Asm[(mrow0 + mt * 16 + l16) * 64 + ((ks * 4 + quad) ^ swz) * 8];
            for (int nt = 0; nt < 4; ++nt) {
                bf16x8 bf = *(const bf16x8*)&Bsm[(ncol0 + nt * 16 + l16) * 64 + ((ks * 4 + quad) ^ swz) * 8];
                for (int mt = 0; mt < 4; ++mt)
                    acc[mt][nt] = mfma_k32(af[mt], bf, acc[mt][nt]);
            }
        }
    }

    if (MODE == 0) {
        bf16_t* out = (bf16_t*)outp;
        for (int nt = 0; nt < 4; ++nt) {
            int e = n0 + ncol0 + nt * 16 + l16;
            int h = e >> 6, el = e & 63;
            for (int mt = 0; mt < 4; ++mt)
                for (int r = 0; r < 4; ++r) {
                    int row = m0 + mrow0 + mt * 16 + quad * 4 + r;   // b*4096+s
                    int b = row >> 12, s = row & 4095;
                    int elp = (((el >> 3) ^ (row & 7)) << 3) | (el & 7);
                    out[(((size_t)(b * 8 + h)) * 4096 + s) * 64 + elp] = (bf16_t)acc[mt][nt][r];
                }
        }
    } else if (MODE == 1) {
        bf16_t* out = (bf16_t*)outp;
        for (int nt = 0; nt < 4; ++nt) {
            int s_g = n0 + ncol0 + nt * 16 + l16;
            int b = s_g >> 12;
            int sbase = (s_g & 4095) & ~63;
            int f = 16 * ((l16 >> 2) & 3) + 4 * nt + (l16 & 3);
            for (int mt = 0; mt < 4; ++mt)
                for (int r = 0; r < 4; ++r) {
                    int e_g = m0 + mrow0 + mt * 16 + quad * 4 + r;
                    int h = e_g >> 6, el = e_g & 63;
                    int col = sbase | ((((f >> 3) ^ (e_g & 7)) & 7) << 3) | (f & 7);
                    out[(((size_t)(b * 8 + h)) * 64 + el) * 4096 + col] = (bf16_t)acc[mt][nt][r];
                }
        }
    } else {
        float* out = (float*)outp;
        for (int nt = 0; nt < 4; ++nt) {
            int n = n0 + ncol0 + nt * 16 + l16;
            for (int mt = 0; mt < 4; ++mt)
                for (int r = 0; r < 4; ++r) {
                    int row = m0 + mrow0 + mt * 16 + quad * 4 + r;
                    out[(size_t)row * 512 + n] = acc[mt][nt][r];
                }
        }
    }
}

__global__ __launch_bounds__(256) void proj_fused(const bf16_t* __restrict__ xs,
                                                  const bf16_t* __restrict__ Wc,
                                                  bf16_t* __restrict__ qh,
                                                  bf16_t* __restrict__ kh,
                                                  bf16_t* __restrict__ vh) {
    const int z = blockIdx.z;
    const bf16_t* X = xs + (size_t)z * 4194304;
    const bf16_t* W = Wc + (size_t)z * 262144;
    if (z == 0)
        gemm128_body<0>(X, W, qh, blockIdx.x * 128, blockIdx.y * 128);
    else if (z == 1)
        gemm128_body<0>(X, W, kh, blockIdx.x * 128, blockIdx.y * 128);
    else
        gemm128_body<1>(W, X, vh, blockIdx.y * 128, blockIdx.x * 128);
}

__global__ __launch_bounds__(256) void gemm_final(const bf16_t* __restrict__ A,
                                                  const bf16_t* __restrict__ B,
                                                  float* __restrict__ out) {
    gemm128_body<2>(A, B, out, blockIdx.x * 128, blockIdx.y * 128);
}

// ---------------------------------------------------------------------------
// Causal flash attention v8: v7 + VALU->MFMA shift, SROA-safe this time.
// v6's regression was rule-#20 scratch (per-element scatter into bf16x8
// defeated SROA -> P round-tripped through HBM: WRITE 36->133 MB at
// unchanged VGPR=64). v8 keeps v7's proven bf16x4 pf[2][4] element inserts,
// then forms bf16x8 p8 via whole-vector __builtin_shufflevector (register
// concat, no scatter). On top of that (both correctness-proven by v6):
//  - PV: 32x mfma k16 -> 16x mfma k32 (V chunk order is slot-exact vs p8).
//  - lsum: 32 v_add/step + leg-end shfl reduces -> 4 ones-MFMA k32/step;
//    lacc[g][r] = exact 64-key row sum for query quad*4+r (replicated
//    across l16). Denominator now sums the same bf16-quantized P as O.
// Tripwire: WRITE_SIZE > 50 MB => SROA failed again => revert to v7.
// ---------------------------------------------------------------------------
__global__ __launch_bounds__(256, 4) void attn_kernel(const bf16_t* __restrict__ qh,
                                                      const bf16_t* __restrict__ kh,
                                                      const bf16_t* __restrict__ vh,
                                                      bf16_t* __restrict__ Opart,
                                                      float* __restrict__ Lpart) {
    __shared__ __bf16 SM[16384];            // 32 KB: K panels [2][64][64] + V panels
    __bf16* KSM = &SM[0];
    __bf16* VSM = &SM[8192];
    float* Osc = (float*)SM;                // 16.6 KB leg-end scratch [q][65]
    float* Lsc = (float*)&SM[8320];         // 256 B lsum scratch [q] (byte 16640)

    const int id   = blockIdx.x;
    const int bh   = ((id & 7) << 1) | ((id >> 3) & 1);   // XCD-grouped
    const int pair = (id >> 4) & 31;
    const int z    = (id >> 9) & 1;

    const int tid  = threadIdx.x;
    const int wave = tid >> 6;
    const int g2   = wave >> 1;             // K-panel parity within step
    const int wl   = wave & 1;              // query half
    const int lane = tid & 63;
    const int quad = lane >> 4;
    const int l16  = lane & 15;
    const int swz  = l16 & 7;
    const size_t base = (size_t)bh * 4096 * 64;
    const int r8 = lane >> 3;
    const int c8 = (lane & 7) * 8;

    bf16x8 ones8;
#pragma unroll
    for (int i = 0; i < 8; ++i) ones8[i] = (bf16_t)1.0f;

    bf16_t* Op = Opart + (size_t)z * 4194304;
    float*  Lp = Lpart + z * 65536;

    for (int leg = 0; leg < 2; ++leg) {
        const int qt = leg ? (63 - pair) : pair;
        const int q0 = qt * 64;

        bf16x8 qf[2][2];
        for (int g = 0; g < 2; ++g) {
            const bf16_t* qp = qh + base + (size_t)(q0 + wl * 32 + g * 16 + l16) * 64;
            qf[g][0] = *(const bf16x8*)(qp + ((quad ^ swz) * 8));
            qf[g][1] = *(const bf16x8*)(qp + (((4 + quad) ^ swz) * 8));
        }

        f32x4 o[2][4];
        for (int g = 0; g < 2; ++g)
            for (int i = 0; i < 4; ++i) o[g][i] = (f32x4){0.f, 0.f, 0.f, 0.f};
        f32x4 lacc[2] = {(f32x4){0.f, 0.f, 0.f, 0.f}, (f32x4){0.f, 0.f, 0.f, 0.f}};

        const int S  = (qt + 2) >> 1;       // total 128-key steps of this leg
        const int Sh = (S + 1) >> 1;        // z=0 takes [0,Sh), z=1 takes [Sh,S)
        const int it0 = z ? Sh : 0;
        const int it1 = z ? S : Sh;

        for (int it = it0; it < it1; ++it) {
            const int j0 = it * 128;
            __syncthreads();
            for (int p = 0; p < 2; ++p)
                for (int j = 0; j < 2; ++j) {
                    int row = wave * 16 + j * 8 + r8;
                    async16(kh + base + (size_t)(j0 + p * 64 + row) * 64 + c8,
                            KSM + (p * 64 + wave * 16 + j * 8) * 64);
                    async16(vh + (size_t)(bh * 64 + row) * 4096 + j0 + p * 64 + c8,
                            VSM + (p * 64 + wave * 16 + j * 8) * 64);
                }
            __syncthreads();

            const int pp = g2;
            const int koff = j0 + pp * 64 - q0;
            if (koff > wl * 32 + 31) continue;     // fully masked for this wave

            // S^T = K·Q^T (C: col=query=l16, row=key=nt*16+quad*4+r)
            f32x4 st[2][4];
            for (int nt = 0; nt < 4; ++nt) {
                const __bf16* kr = KSM + (pp * 64 + nt * 16 + l16) * 64;
                bf16x8 kf0 = *(const bf16x8*)(kr + ((quad ^ swz) * 8));
                bf16x8 kf1 = *(const bf16x8*)(kr + (((4 + quad) ^ swz) * 8));
                for (int g = 0; g < 2; ++g) {
                    f32x4 zz = (f32x4){0.f, 0.f, 0.f, 0.f};
                    zz = mfma_k32(kf0, qf[g][0], zz);
                    zz = mfma_k32(kf1, qf[g][1], zz);
                    st[g][nt] = zz;
                }
            }

            // fixed-base softmax: p = exp2(st) into bf16x4 (v7's proven pattern)
            bf16x4 pf[2][4];
            for (int g = 0; g < 2; ++g) {
                const int qb = wl * 32 + g * 16;
                if (koff + 63 <= qb) {
                    for (int nt = 0; nt < 4; ++nt)
                        for (int r = 0; r < 4; ++r)
                            pf[g][nt][r] = (bf16_t)fast_exp2(st[g][nt][r]);
                } else {
                    const int qrow = qb + l16;
                    for (int nt = 0; nt < 4; ++nt)
                        for (int r = 0; r < 4; ++r) {
                            int key = nt * 16 + quad * 4 + r;
                            float p = (key + koff <= qrow) ? fast_exp2(st[g][nt][r]) : 0.f;
                            pf[g][nt][r] = (bf16_t)p;
                        }
                }
            }

            // pack nt-pairs into bf16x8 via whole-vector shuffle (no scatter)
            bf16x8 p8[2][2];
            for (int g = 0; g < 2; ++g)
                for (int kt2 = 0; kt2 < 2; ++kt2)
                    p8[g][kt2] = __builtin_shufflevector(pf[g][2 * kt2], pf[g][2 * kt2 + 1],
                                                         0, 1, 2, 3, 4, 5, 6, 7);

            // row-sum via ones-MFMA: lacc[g][r] = sum_k P[query=quad*4+r][k]
            for (int g = 0; g < 2; ++g) {
                lacc[g] = mfma_k32(p8[g][0], ones8, lacc[g]);
                lacc[g] = mfma_k32(p8[g][1], ones8, lacc[g]);
            }

            // O += P·V, k32 merged (V chunk order slot-exact vs p8)
            for (int dt = 0; dt < 4; ++dt) {
                const __bf16* vr = VSM + (pp * 64 + dt * 16 + l16) * 64;
                for (int kt2 = 0; kt2 < 2; ++kt2) {
                    bf16x8 vf = *(const bf16x8*)(vr + (((2 * quad + kt2) ^ swz) * 8));
                    o[0][dt] = mfma_k32(p8[0][kt2], vf, o[0][dt]);
                    o[1][dt] = mfma_k32(p8[1][kt2], vf, o[1][dt]);
                }
            }
        }

        // ---- combine K-parity partials within block, write leg partials ----
        __syncthreads();                    // all K/V LDS reads done
        if (g2 == 1) {
            for (int g = 0; g < 2; ++g) {
                const int qb = wl * 32 + g * 16;
                if (l16 == 0)
                    for (int r = 0; r < 4; ++r)
                        Lsc[qb + quad * 4 + r] = lacc[g][r];
                for (int dt = 0; dt < 4; ++dt)
                    for (int r = 0; r < 4; ++r)
                        Osc[(qb + quad * 4 + r) * 65 + dt * 16 + l16] = o[g][dt][r];
            }
        }
        __syncthreads();
        if (g2 == 0) {
            for (int g = 0; g < 2; ++g) {
                const int qb = wl * 32 + g * 16;
                if (l16 == 0)
                    for (int r = 0; r < 4; ++r)
                        Lsc[qb + quad * 4 + r] += lacc[g][r];
                for (int dt = 0; dt < 4; ++dt)
                    for (int r = 0; r < 4; ++r) {
                        int idx = (qb + quad * 4 + r) * 65 + dt * 16 + l16;
                        Osc[idx] = o[g][dt][r] + Osc[idx];
                    }
            }
        }
        __syncthreads();
        // repack: contiguous bf16 partial rows [q][e] + fp32 lsum
        {
            const int q  = tid >> 2;
            const int e0 = (tid & 3) * 16;
            bf16x8 w0, w1;
            for (int i = 0; i < 8; ++i) {
                w0[i] = (bf16_t)Osc[q * 65 + e0 + i];
                w1[i] = (bf16_t)Osc[q * 65 + e0 + 8 + i];
            }
            size_t slot = ((size_t)(bh * 64 + qt)) * 4096 + q * 64 + e0;
            *(bf16x8*)&Op[slot]     = w0;
            *(bf16x8*)&Op[slot + 8] = w1;
            if (tid < 64) Lp[(bh * 64 + qt) * 64 + tid] = Lsc[tid];
        }
        // next leg's first __syncthreads() protects Osc/Lsc reuse
    }
}

// ---------------------------------------------------------------------------
// Combine: sum z-partials, normalize, write swizzled ao. grid 256 x 256 thr.
// ---------------------------------------------------------------------------
__global__ __launch_bounds__(256) void attn_combine(const bf16_t* __restrict__ Opart,
                                                    const float* __restrict__ Lpart,
                                                    bf16_t* __restrict__ ao) {
    const int unit = blockIdx.x * 4 + (threadIdx.x >> 6);  // (bh,qt)
    const int q    = threadIdx.x & 63;
    const int bh = unit >> 6, qt = unit & 63;
    const int b = bh >> 3, h = bh & 7;
    const size_t ro = (size_t)unit * 4096 + q * 64;

    float o[64];
    const bf16x8* p0 = (const bf16x8*)(Opart + ro);
    const bf16x8* p1 = (const bf16x8*)(Opart + 4194304 + ro);
    for (int c = 0; c < 8; ++c) {
        bf16x8 a = p0[c], bb = p1[c];
        for (int i = 0; i < 8; ++i) o[c * 8 + i] = (float)a[i] + (float)bb[i];
    }
    float L = Lpart[unit * 64 + q] + Lpart[65536 + unit * 64 + q];
    float inv = 1.0f / L;
    int s_g = qt * 64 + q, sw = s_g & 7;
    size_t rowoff = ((size_t)(b * 4096 + s_g)) * 512 + h * 64;
    for (int c = 0; c < 8; ++c) {
        int e0 = (c ^ sw) * 8;
        bf16x8 w;
        for (int i = 0; i < 8; ++i) w[i] = (bf16_t)(o[e0 + i] * inv);
        *(bf16x8*)&ao[rowoff + c * 8] = w;
    }
}

// ---------------------------------------------------------------------------
extern "C" void kernel_launch(void* const* d_in, const int* in_sizes, int n_in,
                              void* d_out, int out_size, void* d_ws, size_t ws_size,
                              hipStream_t stream) {
    const float* q  = (const float*)d_in[0];
    const float* k  = (const float*)d_in[1];
    const float* v  = (const float*)d_in[2];
    const float* Wq = (const float*)d_in[3];
    const float* Wk = (const float*)d_in[4];
    const float* Wv = (const float*)d_in[5];
    const float* Wo = (const float*)d_in[6];
    float* out = (float*)d_out;

    bf16_t* ws = (bf16_t*)d_ws;
    const size_t R = (size_t)8192 * 512;   // 4.19M elems = 8.39 MB per region
    bf16_t* qc = ws;                 // R0: q bf16 -> reused as ao
    bf16_t* kc = ws + R;             // R1: k bf16 -> reused as Opart z0
    bf16_t* vc = ws + 2 * R;         // R2: v bf16 -> reused as Opart z1
    bf16_t* vh = ws + 3 * R;         // R3: V^T heads
    bf16_t* Wc = ws + 4 * R;         // +2 MB bf16 weights (Wq pre-scaled)
    float*  Lp = (float*)(ws + 4 * R + 1048576);  // +0.5 MB lsum partials
    bf16_t* qh = (bf16_t*)d_out;     // qh/kh in d_out, dead before final GEMM
    bf16_t* kh = (bf16_t*)d_out + R;
    bf16_t* ao = qc;

    cvt_all<<<dim3(2560), dim3(256), 0, stream>>>(q, k, v, Wq, Wk, Wv, Wo, qc, kc, vc, Wc);
    proj_fused<<<dim3(64, 4, 3), dim3(256), 0, stream>>>(ws, Wc, qh, kh, vh);
    attn_kernel<<<dim3(1024), dim3(256), 0, stream>>>(qh, kh, vh, kc, Lp);
    attn_combine<<<dim3(256), dim3(256), 0, stream>>>(kc, Lp, ao);
    gemm_final<<<dim3(64, 4), dim3(256), 0, stream>>>(ao, Wc + 3 * 262144, out);
}

// Round 4
// 239.356 us; speedup vs baseline: 1.1462x; 1.1462x over previous
//
#include <hip/hip_runtime.h>
#include <hip/hip_bf16.h>
#include <math.h>

typedef __bf16 bf16_t;
typedef __bf16 bf16x8 __attribute__((ext_vector_type(8)));
typedef __bf16 bf16x4 __attribute__((ext_vector_type(4)));
typedef short short4v __attribute__((ext_vector_type(4)));
typedef float f32x4 __attribute__((ext_vector_type(4)));

__device__ __forceinline__ f32x4 mfma_k32(bf16x8 a, bf16x8 b, f32x4 c) {
    return __builtin_amdgcn_mfma_f32_16x16x32_bf16(a, b, c, 0, 0, 0);
}

__device__ __forceinline__ f32x4 mfma_k16(bf16x4 a, bf16x4 b, f32x4 c) {
#if __has_builtin(__builtin_amdgcn_mfma_f32_16x16x16_bf16)
    return __builtin_amdgcn_mfma_f32_16x16x16_bf16(a, b, c, 0, 0, 0);
#elif __has_builtin(__builtin_amdgcn_mfma_f32_16x16x16bf16_1k)
    short4v as, bs;
    __builtin_memcpy(&as, &a, 8);
    __builtin_memcpy(&bs, &b, 8);
    return __builtin_amdgcn_mfma_f32_16x16x16bf16_1k(as, bs, c, 0, 0, 0);
#else
    f32x4 d = c;
    asm volatile("v_mfma_f32_16x16x16_bf16 %0, %1, %2, %0" : "+v"(d) : "v"(a), "v"(b));
    return d;
#endif
}

// raw v_exp_f32 (exp2): avoid OCML guard code around exp2f
__device__ __forceinline__ float fast_exp2(float x) {
#if __has_builtin(__builtin_amdgcn_exp2f)
    return __builtin_amdgcn_exp2f(x);
#else
    float r;
    asm("v_exp_f32 %0, %1" : "=v"(r) : "v"(x));
    return r;
#endif
}

// async global->LDS, 16B/lane; LDS dest = wave-uniform base + lane*16
__device__ __forceinline__ void async16(const bf16_t* g, __bf16* l) {
    __builtin_amdgcn_global_load_lds(
        (const __attribute__((address_space(1))) void*)g,
        (__attribute__((address_space(3))) void*)l, 16, 0, 0);
}

// XOR-swizzle: 16B chunks within each 64-col group, keyed by row&7 (global-side)
__device__ __forceinline__ int swz_col(int col, int row) {
    return (col & ~63) | ((((col >> 3) & 7) ^ (row & 7)) << 3) | (col & 7);
}

// ---------------------------------------------------------------------------
// fp32 -> bf16 swizzled converts, x and W merged into one launch.
// ---------------------------------------------------------------------------
__global__ __launch_bounds__(256) void cvt_all(const float* __restrict__ q,
                                               const float* __restrict__ k,
                                               const float* __restrict__ v,
                                               const float* __restrict__ Wq,
                                               const float* __restrict__ Wk,
                                               const float* __restrict__ Wv,
                                               const float* __restrict__ Wo,
                                               bf16_t* __restrict__ qc,
                                               bf16_t* __restrict__ kc,
                                               bf16_t* __restrict__ vc,
                                               bf16_t* __restrict__ Wc) {
    const int bx = blockIdx.x;
    if (bx < 2048) {
        size_t i = ((size_t)bx * 256 + threadIdx.x) * 8;
        int row = (int)(i >> 9), col = (int)(i & 511);
        size_t di = (size_t)row * 512 + swz_col(col, row);
        float4 a0 = *(const float4*)(q + i), a1 = *(const float4*)(q + i + 4);
        float4 b0 = *(const float4*)(k + i), b1 = *(const float4*)(k + i + 4);
        float4 c0 = *(const float4*)(v + i), c1 = *(const float4*)(v + i + 4);
        bf16x8 qo, ko, vo;
        qo[0]=(__bf16)a0.x; qo[1]=(__bf16)a0.y; qo[2]=(__bf16)a0.z; qo[3]=(__bf16)a0.w;
        qo[4]=(__bf16)a1.x; qo[5]=(__bf16)a1.y; qo[6]=(__bf16)a1.z; qo[7]=(__bf16)a1.w;
        ko[0]=(__bf16)b0.x; ko[1]=(__bf16)b0.y; ko[2]=(__bf16)b0.z; ko[3]=(__bf16)b0.w;
        ko[4]=(__bf16)b1.x; ko[5]=(__bf16)b1.y; ko[6]=(__bf16)b1.z; ko[7]=(__bf16)b1.w;
        vo[0]=(__bf16)c0.x; vo[1]=(__bf16)c0.y; vo[2]=(__bf16)c0.z; vo[3]=(__bf16)c0.w;
        vo[4]=(__bf16)c1.x; vo[5]=(__bf16)c1.y; vo[6]=(__bf16)c1.z; vo[7]=(__bf16)c1.w;
        *(bf16x8*)(qc + di) = qo;
        *(bf16x8*)(kc + di) = ko;
        *(bf16x8*)(vc + di) = vo;
    } else {
        const int b2 = bx - 2048;
        const int m = b2 >> 7;                   // which W
        const float* src = m == 0 ? Wq : m == 1 ? Wk : m == 2 ? Wv : Wo;
        const float sc = (m == 0) ? 0.125f * 1.44269504088896f : 1.0f;
        size_t i = ((size_t)(b2 & 127) * 256 + threadIdx.x) * 8;
        int row = (int)(i >> 9), col = (int)(i & 511);
        float4 a0 = *(const float4*)(src + i), a1 = *(const float4*)(src + i + 4);
        bf16x8 o;
        o[0]=(__bf16)(a0.x*sc); o[1]=(__bf16)(a0.y*sc); o[2]=(__bf16)(a0.z*sc); o[3]=(__bf16)(a0.w*sc);
        o[4]=(__bf16)(a1.x*sc); o[5]=(__bf16)(a1.y*sc); o[6]=(__bf16)(a1.z*sc); o[7]=(__bf16)(a1.w*sc);
        *(bf16x8*)(Wc + (size_t)m * 262144 + (size_t)row * 512 + swz_col(col, row)) = o;
    }
}

// ---------------------------------------------------------------------------
// 128x128-tile NT GEMM (m97 structure) — proj only (control).
// ---------------------------------------------------------------------------
template<int MODE>
__device__ __forceinline__ void gemm128_body(const bf16_t* __restrict__ A,
                                             const bf16_t* __restrict__ B,
                                             void* __restrict__ outp,
                                             int m0, int n0) {
    __shared__ __bf16 Asm[128 * 64];
    __shared__ __bf16 Bsm[128 * 64];
    const int tid  = threadIdx.x;
    const int wave = tid >> 6;
    const int lane = tid & 63;
    const int quad = lane >> 4;
    const int l16  = lane & 15;
    const int swz  = l16 & 7;
    const int r8 = lane >> 3;
    const int c8 = (lane & 7) * 8;
    const int mrow0 = (wave & 1) * 64;
    const int ncol0 = (wave >> 1) * 64;

    f32x4 acc[4][4];
    for (int i = 0; i < 4; ++i)
        for (int j = 0; j < 4; ++j) acc[i][j] = (f32x4){0.f, 0.f, 0.f, 0.f};

    for (int kt = 0; kt < 512; kt += 64) {
        __syncthreads();
        for (int j = 0; j < 4; ++j) {
            async16(A + (size_t)(m0 + wave * 32 + j * 8 + r8) * 512 + kt + c8,
                    &Asm[(wave * 32 + j * 8) * 64]);
            async16(B + (size_t)(n0 + wave * 32 + j * 8 + r8) * 512 + kt + c8,
                    &Bsm[(wave * 32 + j * 8) * 64]);
        }
        __syncthreads();

        for (int ks = 0; ks < 2; ++ks) {
            bf16x8 af[4];
            for (int mt = 0; mt < 4; ++mt)
                af[mt] = *(const bf16x8*)&Asm[(mrow0 + mt * 16 + l16) * 64 + ((ks * 4 + quad) ^ swz) * 8];
            for (int nt = 0; nt < 4; ++nt) {
                bf16x8 bf = *(const bf16x8*)&Bsm[(ncol0 + nt * 16 + l16) * 64 + ((ks * 4 + quad) ^ swz) * 8];
                for (int mt = 0; mt < 4; ++mt)
                    acc[mt][nt] = mfma_k32(af[mt], bf, acc[mt][nt]);
            }
        }
    }

    if (MODE == 0) {
        bf16_t* out = (bf16_t*)outp;
        for (int nt = 0; nt < 4; ++nt) {
            int e = n0 + ncol0 + nt * 16 + l16;
            int h = e >> 6, el = e & 63;
            for (int mt = 0; mt < 4; ++mt)
                for (int r = 0; r < 4; ++r) {
                    int row = m0 + mrow0 + mt * 16 + quad * 4 + r;   // b*4096+s
                    int b = row >> 12, s = row & 4095;
                    int elp = (((el >> 3) ^ (row & 7)) << 3) | (el & 7);
                    out[(((size_t)(b * 8 + h)) * 4096 + s) * 64 + elp] = (bf16_t)acc[mt][nt][r];
                }
        }
    } else {
        bf16_t* out = (bf16_t*)outp;
        for (int nt = 0; nt < 4; ++nt) {
            int s_g = n0 + ncol0 + nt * 16 + l16;
            int b = s_g >> 12;
            int sbase = (s_g & 4095) & ~63;
            int f = 16 * ((l16 >> 2) & 3) + 4 * nt + (l16 & 3);
            for (int mt = 0; mt < 4; ++mt)
                for (int r = 0; r < 4; ++r) {
                    int e_g = m0 + mrow0 + mt * 16 + quad * 4 + r;
                    int h = e_g >> 6, el = e_g & 63;
                    int col = sbase | ((((f >> 3) ^ (e_g & 7)) & 7) << 3) | (f & 7);
                    out[(((size_t)(b * 8 + h)) * 64 + el) * 4096 + col] = (bf16_t)acc[mt][nt][r];
                }
        }
    }
}

__global__ __launch_bounds__(256) void proj_fused(const bf16_t* __restrict__ xs,
                                                  const bf16_t* __restrict__ Wc,
                                                  bf16_t* __restrict__ qh,
                                                  bf16_t* __restrict__ kh,
                                                  bf16_t* __restrict__ vh) {
    const int z = blockIdx.z;
    const bf16_t* X = xs + (size_t)z * 4194304;
    const bf16_t* W = Wc + (size_t)z * 262144;
    if (z == 0)
        gemm128_body<0>(X, W, qh, blockIdx.x * 128, blockIdx.y * 128);
    else if (z == 1)
        gemm128_body<0>(X, W, kh, blockIdx.x * 128, blockIdx.y * 128);
    else
        gemm128_body<1>(W, X, vh, blockIdx.y * 128, blockIdx.x * 128);
}

// ---------------------------------------------------------------------------
// Final GEMM with fused z-combine + softmax normalization (replaces the
// separate attn_combine kernel). Key fact: each K-step kt covers exactly one
// head h = kt>>6, and the softmax normalizer is per (b,h,s) -> fold
// (Op0+Op1)*inv(L0+L1) into the A-staging: reg-load 16B from each partial,
// sum+scale in f32, convert, swizzled ds_write_b128 (chunk^r8 Latin square,
// same conflict-free geometry as the inner-loop reads). B path (Wo) and the
// MFMA loop are unchanged from the m97 structure.
// ---------------------------------------------------------------------------
__global__ __launch_bounds__(256) void gemm_final(const bf16_t* __restrict__ Op,
                                                  const float* __restrict__ Lp,
                                                  const bf16_t* __restrict__ B,
                                                  float* __restrict__ out) {
    __shared__ __bf16 Asm[128 * 64];
    __shared__ __bf16 Bsm[128 * 64];
    const int m0 = blockIdx.x * 128, n0 = blockIdx.y * 128;
    const int tid  = threadIdx.x;
    const int wave = tid >> 6;
    const int lane = tid & 63;
    const int quad = lane >> 4;
    const int l16  = lane & 15;
    const int swz  = l16 & 7;
    const int r8 = lane >> 3;
    const int c8 = (lane & 7) * 8;
    const int mrow0 = (wave & 1) * 64;
    const int ncol0 = (wave >> 1) * 64;

    f32x4 acc[4][4];
    for (int i = 0; i < 4; ++i)
        for (int j = 0; j < 4; ++j) acc[i][j] = (f32x4){0.f, 0.f, 0.f, 0.f};

    for (int kt = 0; kt < 512; kt += 64) {
        const int h = kt >> 6;
        __syncthreads();
        for (int j = 0; j < 4; ++j)
            async16(B + (size_t)(n0 + wave * 32 + j * 8 + r8) * 512 + kt + c8,
                    &Bsm[(wave * 32 + j * 8) * 64]);
        for (int j = 0; j < 4; ++j) {
            const int rl  = wave * 32 + j * 8 + r8;
            const int row = m0 + rl;                 // b*4096 + s
            const int b   = row >> 12, sp = row & 4095;
            const size_t lidx = (size_t)(b * 8 + h) * 4096 + sp;
            bf16x8 a0 = *(const bf16x8*)(Op + lidx * 64 + c8);
            bf16x8 a1 = *(const bf16x8*)(Op + 4194304 + lidx * 64 + c8);
            float inv = 1.0f / (Lp[lidx] + Lp[65536 + lidx]);
            bf16x8 w;
            for (int i = 0; i < 8; ++i)
                w[i] = (bf16_t)(((float)a0[i] + (float)a1[i]) * inv);
            *(bf16x8*)&Asm[rl * 64 + (((lane & 7) ^ r8) << 3)] = w;
        }
        __syncthreads();

        for (int ks = 0; ks < 2; ++ks) {
            bf16x8 af[4];
            for (int mt = 0; mt < 4; ++mt)
                af[mt] = *(const bf16x8*)&Asm[(mrow0 + mt * 16 + l16) * 64 + ((ks * 4 + quad) ^ swz) * 8];
            for (int nt = 0; nt < 4; ++nt) {
                bf16x8 bf = *(const bf16x8*)&Bsm[(ncol0 + nt * 16 + l16) * 64 + ((ks * 4 + quad) ^ swz) * 8];
                for (int mt = 0; mt < 4; ++mt)
                    acc[mt][nt] = mfma_k32(af[mt], bf, acc[mt][nt]);
            }
        }
    }

    for (int nt = 0; nt < 4; ++nt) {
        int n = n0 + ncol0 + nt * 16 + l16;
        for (int mt = 0; mt < 4; ++mt)
            for (int r = 0; r < 4; ++r) {
                int row = m0 + mrow0 + mt * 16 + quad * 4 + r;
                out[(size_t)row * 512 + n] = acc[mt][nt][r];
            }
    }
}

// ---------------------------------------------------------------------------
// Causal flash attention v7 (verbatim R2 winner, 62.6us): v5 compute
// structure + Osc stride-65 padding. The k32/ones-MFMA restructure is
// permanently abandoned (two independent constructions both scratch-demoted:
// WRITE 36->134 MB at unchanged VGPR=64).
// ---------------------------------------------------------------------------
__global__ __launch_bounds__(256, 4) void attn_kernel(const bf16_t* __restrict__ qh,
                                                      const bf16_t* __restrict__ kh,
                                                      const bf16_t* __restrict__ vh,
                                                      bf16_t* __restrict__ Opart,
                                                      float* __restrict__ Lpart) {
    __shared__ __bf16 SM[16384];            // 32 KB: K panels [2][64][64] + V panels
    __bf16* KSM = &SM[0];
    __bf16* VSM = &SM[8192];
    float* Osc = (float*)SM;                // 16.6 KB leg-end scratch [q][65]
    float* Lsc = (float*)&SM[8320];         // 256 B lsum scratch [q] (byte 16640)

    const int id   = blockIdx.x;
    const int bh   = ((id & 7) << 1) | ((id >> 3) & 1);   // XCD-grouped
    const int pair = (id >> 4) & 31;
    const int z    = (id >> 9) & 1;

    const int tid  = threadIdx.x;
    const int wave = tid >> 6;
    const int g2   = wave >> 1;             // K-panel parity within step
    const int wl   = wave & 1;              // query half
    const int lane = tid & 63;
    const int quad = lane >> 4;
    const int l16  = lane & 15;
    const int swz  = l16 & 7;
    const size_t base = (size_t)bh * 4096 * 64;
    const int r8 = lane >> 3;
    const int c8 = (lane & 7) * 8;

    bf16_t* Op = Opart + (size_t)z * 4194304;
    float*  Lp = Lpart + z * 65536;

    for (int leg = 0; leg < 2; ++leg) {
        const int qt = leg ? (63 - pair) : pair;
        const int q0 = qt * 64;

        bf16x8 qf[2][2];
        for (int g = 0; g < 2; ++g) {
            const bf16_t* qp = qh + base + (size_t)(q0 + wl * 32 + g * 16 + l16) * 64;
            qf[g][0] = *(const bf16x8*)(qp + ((quad ^ swz) * 8));
            qf[g][1] = *(const bf16x8*)(qp + (((4 + quad) ^ swz) * 8));
        }

        f32x4 o[2][4];
        for (int g = 0; g < 2; ++g)
            for (int i = 0; i < 4; ++i) o[g][i] = (f32x4){0.f, 0.f, 0.f, 0.f};
        float lsum[2] = {0.f, 0.f};

        const int S  = (qt + 2) >> 1;       // total 128-key steps of this leg
        const int Sh = (S + 1) >> 1;        // z=0 takes [0,Sh), z=1 takes [Sh,S)
        const int it0 = z ? Sh : 0;
        const int it1 = z ? S : Sh;

        for (int it = it0; it < it1; ++it) {
            const int j0 = it * 128;
            __syncthreads();
            for (int p = 0; p < 2; ++p)
                for (int j = 0; j < 2; ++j) {
                    int row = wave * 16 + j * 8 + r8;
                    async16(kh + base + (size_t)(j0 + p * 64 + row) * 64 + c8,
                            KSM + (p * 64 + wave * 16 + j * 8) * 64);
                    async16(vh + (size_t)(bh * 64 + row) * 4096 + j0 + p * 64 + c8,
                            VSM + (p * 64 + wave * 16 + j * 8) * 64);
                }
            __syncthreads();

            const int pp = g2;
            const int koff = j0 + pp * 64 - q0;
            if (koff > wl * 32 + 31) continue;     // fully masked for this wave

            // S^T = K·Q^T (C: col=query=l16, row=key=nt*16+quad*4+r)
            f32x4 st[2][4];
            for (int nt = 0; nt < 4; ++nt) {
                const __bf16* kr = KSM + (pp * 64 + nt * 16 + l16) * 64;
                bf16x8 kf0 = *(const bf16x8*)(kr + ((quad ^ swz) * 8));
                bf16x8 kf1 = *(const bf16x8*)(kr + (((4 + quad) ^ swz) * 8));
                for (int g = 0; g < 2; ++g) {
                    f32x4 zz = (f32x4){0.f, 0.f, 0.f, 0.f};
                    zz = mfma_k32(kf0, qf[g][0], zz);
                    zz = mfma_k32(kf1, qf[g][1], zz);
                    st[g][nt] = zz;
                }
            }

            // fixed-base softmax: p = exp2(st)
            bf16x4 pf[2][4];
            for (int g = 0; g < 2; ++g) {
                const int qb = wl * 32 + g * 16;
                if (koff + 63 <= qb) {
                    for (int nt = 0; nt < 4; ++nt)
                        for (int r = 0; r < 4; ++r) {
                            float p = fast_exp2(st[g][nt][r]);
                            lsum[g] += p;
                            pf[g][nt][r] = (bf16_t)p;
                        }
                } else {
                    const int qrow = qb + l16;
                    for (int nt = 0; nt < 4; ++nt)
                        for (int r = 0; r < 4; ++r) {
                            int key = nt * 16 + quad * 4 + r;
                            float p = (key + koff <= qrow) ? fast_exp2(st[g][nt][r]) : 0.f;
                            lsum[g] += p;
                            pf[g][nt][r] = (bf16_t)p;
                        }
                }
            }

            // O += P·V (P register-resident)
            for (int dt = 0; dt < 4; ++dt)
                for (int kt2 = 0; kt2 < 2; ++kt2) {
                    bf16x8 vf = *(const bf16x8*)&VSM[(pp * 64 + dt * 16 + l16) * 64 + (((2 * quad + kt2) ^ swz) * 8)];
                    bf16x4 vlo = {vf[0], vf[1], vf[2], vf[3]};
                    bf16x4 vhi = {vf[4], vf[5], vf[6], vf[7]};
                    for (int g = 0; g < 2; ++g) {
                        o[g][dt] = mfma_k16(pf[g][2 * kt2], vlo, o[g][dt]);
                        o[g][dt] = mfma_k16(pf[g][2 * kt2 + 1], vhi, o[g][dt]);
                    }
                }
        }

        // ---- combine K-parity partials within block, write leg partials ----
        __syncthreads();                    // all K/V LDS reads done
        if (g2 == 1) {
            for (int g = 0; g < 2; ++g) {
                float ls = lsum[g];
                ls += __shfl_xor(ls, 16);
                ls += __shfl_xor(ls, 32);
                const int qb = wl * 32 + g * 16;
                Lsc[qb + l16] = ls;
                for (int dt = 0; dt < 4; ++dt)
                    for (int r = 0; r < 4; ++r)
                        Osc[(qb + quad * 4 + r) * 65 + dt * 16 + l16] = o[g][dt][r];
            }
        }
        __syncthreads();
        if (g2 == 0) {
            for (int g = 0; g < 2; ++g) {
                float ls = lsum[g];
                ls += __shfl_xor(ls, 16);
                ls += __shfl_xor(ls, 32);
                const int qb = wl * 32 + g * 16;
                ls += Lsc[qb + l16];
                Lsc[qb + l16] = ls;         // total lsum for this z
                for (int dt = 0; dt < 4; ++dt)
                    for (int r = 0; r < 4; ++r) {
                        int idx = (qb + quad * 4 + r) * 65 + dt * 16 + l16;
                        Osc[idx] = o[g][dt][r] + Osc[idx];
                    }
            }
        }
        __syncthreads();
        // repack: contiguous bf16 partial rows [q][e] + fp32 lsum
        {
            const int q  = tid >> 2;
            const int e0 = (tid & 3) * 16;
            bf16x8 w0, w1;
            for (int i = 0; i < 8; ++i) {
                w0[i] = (bf16_t)Osc[q * 65 + e0 + i];
                w1[i] = (bf16_t)Osc[q * 65 + e0 + 8 + i];
            }
            size_t slot = ((size_t)(bh * 64 + qt)) * 4096 + q * 64 + e0;
            *(bf16x8*)&Op[slot]     = w0;
            *(bf16x8*)&Op[slot + 8] = w1;
            if (tid < 64) Lp[(bh * 64 + qt) * 64 + tid] = Lsc[tid];
        }
        // next leg's first __syncthreads() protects Osc/Lsc reuse
    }
}

// ---------------------------------------------------------------------------
extern "C" void kernel_launch(void* const* d_in, const int* in_sizes, int n_in,
                              void* d_out, int out_size, void* d_ws, size_t ws_size,
                              hipStream_t stream) {
    const float* q  = (const float*)d_in[0];
    const float* k  = (const float*)d_in[1];
    const float* v  = (const float*)d_in[2];
    const float* Wq = (const float*)d_in[3];
    const float* Wk = (const float*)d_in[4];
    const float* Wv = (const float*)d_in[5];
    const float* Wo = (const float*)d_in[6];
    float* out = (float*)d_out;

    bf16_t* ws = (bf16_t*)d_ws;
    const size_t R = (size_t)8192 * 512;   // 4.19M elems = 8.39 MB per region
    bf16_t* qc = ws;                 // R0: q bf16
    bf16_t* kc = ws + R;             // R1: k bf16 -> reused as Opart z0
    bf16_t* vc = ws + 2 * R;         // R2: v bf16 -> reused as Opart z1
    bf16_t* vh = ws + 3 * R;         // R3: V^T heads
    bf16_t* Wc = ws + 4 * R;         // +2 MB bf16 weights (Wq pre-scaled)
    float*  Lp = (float*)(ws + 4 * R + 1048576);  // +0.5 MB lsum partials
    bf16_t* qh = (bf16_t*)d_out;     // qh/kh in d_out, dead before final GEMM
    bf16_t* kh = (bf16_t*)d_out + R;

    cvt_all<<<dim3(2560), dim3(256), 0, stream>>>(q, k, v, Wq, Wk, Wv, Wo, qc, kc, vc, Wc);
    proj_fused<<<dim3(64, 4, 3), dim3(256), 0, stream>>>(ws, Wc, qh, kh, vh);
    attn_kernel<<<dim3(1024), dim3(256), 0, stream>>>(qh, kh, vh, kc, Lp);
    gemm_final<<<dim3(64, 4), dim3(256), 0, stream>>>(kc, Lp, Wc + 3 * 262144, out);
}

// Round 5
// 239.152 us; speedup vs baseline: 1.1472x; 1.0009x over previous
//
#include <hip/hip_runtime.h>
#include <hip/hip_bf16.h>
#include <math.h>

typedef __bf16 bf16_t;
typedef __bf16 bf16x8 __attribute__((ext_vector_type(8)));
typedef __bf16 bf16x4 __attribute__((ext_vector_type(4)));
typedef short short4v __attribute__((ext_vector_type(4)));
typedef float f32x4 __attribute__((ext_vector_type(4)));

__device__ __forceinline__ f32x4 mfma_k32(bf16x8 a, bf16x8 b, f32x4 c) {
    return __builtin_amdgcn_mfma_f32_16x16x32_bf16(a, b, c, 0, 0, 0);
}

__device__ __forceinline__ f32x4 mfma_k16(bf16x4 a, bf16x4 b, f32x4 c) {
#if __has_builtin(__builtin_amdgcn_mfma_f32_16x16x16_bf16)
    return __builtin_amdgcn_mfma_f32_16x16x16_bf16(a, b, c, 0, 0, 0);
#elif __has_builtin(__builtin_amdgcn_mfma_f32_16x16x16bf16_1k)
    short4v as, bs;
    __builtin_memcpy(&as, &a, 8);
    __builtin_memcpy(&bs, &b, 8);
    return __builtin_amdgcn_mfma_f32_16x16x16bf16_1k(as, bs, c, 0, 0, 0);
#else
    f32x4 d = c;
    asm volatile("v_mfma_f32_16x16x16_bf16 %0, %1, %2, %0" : "+v"(d) : "v"(a), "v"(b));
    return d;
#endif
}

// raw v_exp_f32 (exp2): avoid OCML guard code around exp2f
__device__ __forceinline__ float fast_exp2(float x) {
#if __has_builtin(__builtin_amdgcn_exp2f)
    return __builtin_amdgcn_exp2f(x);
#else
    float r;
    asm("v_exp_f32 %0, %1" : "=v"(r) : "v"(x));
    return r;
#endif
}

// async global->LDS, 16B/lane; LDS dest = wave-uniform base + lane*16
__device__ __forceinline__ void async16(const bf16_t* g, __bf16* l) {
    __builtin_amdgcn_global_load_lds(
        (const __attribute__((address_space(1))) void*)g,
        (__attribute__((address_space(3))) void*)l, 16, 0, 0);
}

// XOR-swizzle: 16B chunks within each 64-col group, keyed by row&7 (global-side)
__device__ __forceinline__ int swz_col(int col, int row) {
    return (col & ~63) | ((((col >> 3) & 7) ^ (row & 7)) << 3) | (col & 7);
}

__device__ __forceinline__ bf16x8 cvt8(float4 a, float4 b) {
    bf16x8 w;
    w[0]=(__bf16)a.x; w[1]=(__bf16)a.y; w[2]=(__bf16)a.z; w[3]=(__bf16)a.w;
    w[4]=(__bf16)b.x; w[5]=(__bf16)b.y; w[6]=(__bf16)b.z; w[7]=(__bf16)b.w;
    return w;
}

// ---------------------------------------------------------------------------
// fp32 -> bf16 swizzled convert, W only (x conversion now fused into proj).
// ---------------------------------------------------------------------------
__global__ __launch_bounds__(256) void cvt_W(const float* __restrict__ Wq,
                                             const float* __restrict__ Wk,
                                             const float* __restrict__ Wv,
                                             const float* __restrict__ Wo,
                                             bf16_t* __restrict__ Wc) {
    const int b2 = blockIdx.x;
    const int m = b2 >> 7;                   // which W
    const float* src = m == 0 ? Wq : m == 1 ? Wk : m == 2 ? Wv : Wo;
    const float sc = (m == 0) ? 0.125f * 1.44269504088896f : 1.0f;
    size_t i = ((size_t)(b2 & 127) * 256 + threadIdx.x) * 8;
    int row = (int)(i >> 9), col = (int)(i & 511);
    float4 a0 = *(const float4*)(src + i), a1 = *(const float4*)(src + i + 4);
    bf16x8 o;
    o[0]=(__bf16)(a0.x*sc); o[1]=(__bf16)(a0.y*sc); o[2]=(__bf16)(a0.z*sc); o[3]=(__bf16)(a0.w*sc);
    o[4]=(__bf16)(a1.x*sc); o[5]=(__bf16)(a1.y*sc); o[6]=(__bf16)(a1.z*sc); o[7]=(__bf16)(a1.w*sc);
    *(bf16x8*)(Wc + (size_t)m * 262144 + (size_t)row * 512 + swz_col(col, row)) = o;
}

// ---------------------------------------------------------------------------
// 128x128-tile NT GEMM (m97 structure), per-operand staging:
//   AF32/BF32 = 1: operand is fp32 in global; reg-load 32B/lane, convert,
//     Latin-square-swizzled ds_write_b128 (chunk^(row&7) — the exact pattern
//     proven in R4's fused gemm_final staging; conflict-free, and matches
//     what the swizzled LDS readers expect).
//   AF32/BF32 = 0: operand is pre-swizzled bf16; global_load_lds direct.
// ---------------------------------------------------------------------------
template<int MODE, int AF32, int BF32>
__device__ __forceinline__ void gemm128_body(const bf16_t* __restrict__ Ab,
                                             const float* __restrict__ Af,
                                             const bf16_t* __restrict__ Bb,
                                             const float* __restrict__ Bf,
                                             void* __restrict__ outp,
                                             int m0, int n0) {
    __shared__ __bf16 Asm[128 * 64];
    __shared__ __bf16 Bsm[128 * 64];
    const int tid  = threadIdx.x;
    const int wave = tid >> 6;
    const int lane = tid & 63;
    const int quad = lane >> 4;
    const int l16  = lane & 15;
    const int swz  = l16 & 7;
    const int r8 = lane >> 3;
    const int c8 = (lane & 7) * 8;
    const int mrow0 = (wave & 1) * 64;
    const int ncol0 = (wave >> 1) * 64;

    f32x4 acc[4][4];
    for (int i = 0; i < 4; ++i)
        for (int j = 0; j < 4; ++j) acc[i][j] = (f32x4){0.f, 0.f, 0.f, 0.f};

    for (int kt = 0; kt < 512; kt += 64) {
        __syncthreads();
        for (int j = 0; j < 4; ++j) {
            const int rl = wave * 32 + j * 8 + r8;
            if (AF32) {
                const float* s = Af + (size_t)(m0 + rl) * 512 + kt + c8;
                float4 v0 = *(const float4*)s, v1 = *(const float4*)(s + 4);
                *(bf16x8*)&Asm[rl * 64 + (((lane & 7) ^ r8) << 3)] = cvt8(v0, v1);
            } else {
                async16(Ab + (size_t)(m0 + rl) * 512 + kt + c8,
                        &Asm[(wave * 32 + j * 8) * 64]);
            }
            if (BF32) {
                const float* s = Bf + (size_t)(n0 + rl) * 512 + kt + c8;
                float4 v0 = *(const float4*)s, v1 = *(const float4*)(s + 4);
                *(bf16x8*)&Bsm[rl * 64 + (((lane & 7) ^ r8) << 3)] = cvt8(v0, v1);
            } else {
                async16(Bb + (size_t)(n0 + rl) * 512 + kt + c8,
                        &Bsm[(wave * 32 + j * 8) * 64]);
            }
        }
        __syncthreads();

        for (int ks = 0; ks < 2; ++ks) {
            bf16x8 af[4];
            for (int mt = 0; mt < 4; ++mt)
                af[mt] = *(const bf16x8*)&Asm[(mrow0 + mt * 16 + l16) * 64 + ((ks * 4 + quad) ^ swz) * 8];
            for (int nt = 0; nt < 4; ++nt) {
                bf16x8 bf = *(const bf16x8*)&Bsm[(ncol0 + nt * 16 + l16) * 64 + ((ks * 4 + quad) ^ swz) * 8];
                for (int mt = 0; mt < 4; ++mt)
                    acc[mt][nt] = mfma_k32(af[mt], bf, acc[mt][nt]);
            }
        }
    }

    if (MODE == 0) {
        bf16_t* out = (bf16_t*)outp;
        for (int nt = 0; nt < 4; ++nt) {
            int e = n0 + ncol0 + nt * 16 + l16;
            int h = e >> 6, el = e & 63;
            for (int mt = 0; mt < 4; ++mt)
                for (int r = 0; r < 4; ++r) {
                    int row = m0 + mrow0 + mt * 16 + quad * 4 + r;   // b*4096+s
                    int b = row >> 12, s = row & 4095;
                    int elp = (((el >> 3) ^ (row & 7)) << 3) | (el & 7);
                    out[(((size_t)(b * 8 + h)) * 4096 + s) * 64 + elp] = (bf16_t)acc[mt][nt][r];
                }
        }
    } else {
        bf16_t* out = (bf16_t*)outp;
        for (int nt = 0; nt < 4; ++nt) {
            int s_g = n0 + ncol0 + nt * 16 + l16;
            int b = s_g >> 12;
            int sbase = (s_g & 4095) & ~63;
            int f = 16 * ((l16 >> 2) & 3) + 4 * nt + (l16 & 3);
            for (int mt = 0; mt < 4; ++mt)
                for (int r = 0; r < 4; ++r) {
                    int e_g = m0 + mrow0 + mt * 16 + quad * 4 + r;
                    int h = e_g >> 6, el = e_g & 63;
                    int col = sbase | ((((f >> 3) ^ (e_g & 7)) & 7) << 3) | (f & 7);
                    out[(((size_t)(b * 8 + h)) * 64 + el) * 4096 + col] = (bf16_t)acc[mt][nt][r];
                }
        }
    }
}

// grid (256,1,3); XCD-sibling swizzle: same-A-stripe blocks (4 y's) get ids
// 8 apart -> same XCD (round-robin) -> stripe L2-served instead of 4x HBM.
__global__ __launch_bounds__(256) void proj_fused(const float* __restrict__ q,
                                                  const float* __restrict__ k,
                                                  const float* __restrict__ v,
                                                  const bf16_t* __restrict__ Wc,
                                                  bf16_t* __restrict__ qh,
                                                  bf16_t* __restrict__ kh,
                                                  bf16_t* __restrict__ vh) {
    const int f = blockIdx.x;
    const int y = (f >> 3) & 3;
    const int x = (f & 7) | ((f >> 5) << 3);
    const int z = blockIdx.z;
    const bf16_t* W = Wc + (size_t)z * 262144;
    if (z == 0)
        gemm128_body<0, 1, 0>(nullptr, q, W, nullptr, qh, x * 128, y * 128);
    else if (z == 1)
        gemm128_body<0, 1, 0>(nullptr, k, W, nullptr, kh, x * 128, y * 128);
    else
        gemm128_body<1, 0, 1>(W, nullptr, nullptr, v, vh, y * 128, x * 128);
}

// ---------------------------------------------------------------------------
// Final GEMM with fused z-combine + softmax normalization (proven in R4),
// plus the same XCD-sibling grid swizzle.
// ---------------------------------------------------------------------------
__global__ __launch_bounds__(256) void gemm_final(const bf16_t* __restrict__ Op,
                                                  const float* __restrict__ Lp,
                                                  const bf16_t* __restrict__ B,
                                                  float* __restrict__ out) {
    __shared__ __bf16 Asm[128 * 64];
    __shared__ __bf16 Bsm[128 * 64];
    const int fb = blockIdx.x;
    const int m0 = ((fb & 7) | ((fb >> 5) << 3)) * 128;
    const int n0 = ((fb >> 3) & 3) * 128;
    const int tid  = threadIdx.x;
    const int wave = tid >> 6;
    const int lane = tid & 63;
    const int quad = lane >> 4;
    const int l16  = lane & 15;
    const int swz  = l16 & 7;
    const int r8 = lane >> 3;
    const int c8 = (lane & 7) * 8;
    const int mrow0 = (wave & 1) * 64;
    const int ncol0 = (wave >> 1) * 64;

    f32x4 acc[4][4];
    for (int i = 0; i < 4; ++i)
        for (int j = 0; j < 4; ++j) acc[i][j] = (f32x4){0.f, 0.f, 0.f, 0.f};

    for (int kt = 0; kt < 512; kt += 64) {
        const int h = kt >> 6;
        __syncthreads();
        for (int j = 0; j < 4; ++j)
            async16(B + (size_t)(n0 + wave * 32 + j * 8 + r8) * 512 + kt + c8,
                    &Bsm[(wave * 32 + j * 8) * 64]);
        for (int j = 0; j < 4; ++j) {
            const int rl  = wave * 32 + j * 8 + r8;
            const int row = m0 + rl;                 // b*4096 + s
            const int b   = row >> 12, sp = row & 4095;
            const size_t lidx = (size_t)(b * 8 + h) * 4096 + sp;
            bf16x8 a0 = *(const bf16x8*)(Op + lidx * 64 + c8);
            bf16x8 a1 = *(const bf16x8*)(Op + 4194304 + lidx * 64 + c8);
            float inv = 1.0f / (Lp[lidx] + Lp[65536 + lidx]);
            bf16x8 w;
            for (int i = 0; i < 8; ++i)
                w[i] = (bf16_t)(((float)a0[i] + (float)a1[i]) * inv);
            *(bf16x8*)&Asm[rl * 64 + (((lane & 7) ^ r8) << 3)] = w;
        }
        __syncthreads();

        for (int ks = 0; ks < 2; ++ks) {
            bf16x8 af[4];
            for (int mt = 0; mt < 4; ++mt)
                af[mt] = *(const bf16x8*)&Asm[(mrow0 + mt * 16 + l16) * 64 + ((ks * 4 + quad) ^ swz) * 8];
            for (int nt = 0; nt < 4; ++nt) {
                bf16x8 bf = *(const bf16x8*)&Bsm[(ncol0 + nt * 16 + l16) * 64 + ((ks * 4 + quad) ^ swz) * 8];
                for (int mt = 0; mt < 4; ++mt)
                    acc[mt][nt] = mfma_k32(af[mt], bf, acc[mt][nt]);
            }
        }
    }

    for (int nt = 0; nt < 4; ++nt) {
        int n = n0 + ncol0 + nt * 16 + l16;
        for (int mt = 0; mt < 4; ++mt)
            for (int r = 0; r < 4; ++r) {
                int row = m0 + mrow0 + mt * 16 + quad * 4 + r;
                out[(size_t)row * 512 + n] = acc[mt][nt][r];
            }
    }
}

// ---------------------------------------------------------------------------
// Causal flash attention v7 (verbatim R2 winner, 62.6us): v5 compute
// structure + Osc stride-65 padding. k32/ones-MFMA restructure permanently
// abandoned (two constructions both scratch-demoted).
// ---------------------------------------------------------------------------
__global__ __launch_bounds__(256, 4) void attn_kernel(const bf16_t* __restrict__ qh,
                                                      const bf16_t* __restrict__ kh,
                                                      const bf16_t* __restrict__ vh,
                                                      bf16_t* __restrict__ Opart,
                                                      float* __restrict__ Lpart) {
    __shared__ __bf16 SM[16384];            // 32 KB: K panels [2][64][64] + V panels
    __bf16* KSM = &SM[0];
    __bf16* VSM = &SM[8192];
    float* Osc = (float*)SM;                // 16.6 KB leg-end scratch [q][65]
    float* Lsc = (float*)&SM[8320];         // 256 B lsum scratch [q] (byte 16640)

    const int id   = blockIdx.x;
    const int bh   = ((id & 7) << 1) | ((id >> 3) & 1);   // XCD-grouped
    const int pair = (id >> 4) & 31;
    const int z    = (id >> 9) & 1;

    const int tid  = threadIdx.x;
    const int wave = tid >> 6;
    const int g2   = wave >> 1;             // K-panel parity within step
    const int wl   = wave & 1;              // query half
    const int lane = tid & 63;
    const int quad = lane >> 4;
    const int l16  = lane & 15;
    const int swz  = l16 & 7;
    const size_t base = (size_t)bh * 4096 * 64;
    const int r8 = lane >> 3;
    const int c8 = (lane & 7) * 8;

    bf16_t* Op = Opart + (size_t)z * 4194304;
    float*  Lp = Lpart + z * 65536;

    for (int leg = 0; leg < 2; ++leg) {
        const int qt = leg ? (63 - pair) : pair;
        const int q0 = qt * 64;

        bf16x8 qf[2][2];
        for (int g = 0; g < 2; ++g) {
            const bf16_t* qp = qh + base + (size_t)(q0 + wl * 32 + g * 16 + l16) * 64;
            qf[g][0] = *(const bf16x8*)(qp + ((quad ^ swz) * 8));
            qf[g][1] = *(const bf16x8*)(qp + (((4 + quad) ^ swz) * 8));
        }

        f32x4 o[2][4];
        for (int g = 0; g < 2; ++g)
            for (int i = 0; i < 4; ++i) o[g][i] = (f32x4){0.f, 0.f, 0.f, 0.f};
        float lsum[2] = {0.f, 0.f};

        const int S  = (qt + 2) >> 1;       // total 128-key steps of this leg
        const int Sh = (S + 1) >> 1;        // z=0 takes [0,Sh), z=1 takes [Sh,S)
        const int it0 = z ? Sh : 0;
        const int it1 = z ? S : Sh;

        for (int it = it0; it < it1; ++it) {
            const int j0 = it * 128;
            __syncthreads();
            for (int p = 0; p < 2; ++p)
                for (int j = 0; j < 2; ++j) {
                    int row = wave * 16 + j * 8 + r8;
                    async16(kh + base + (size_t)(j0 + p * 64 + row) * 64 + c8,
                            KSM + (p * 64 + wave * 16 + j * 8) * 64);
                    async16(vh + (size_t)(bh * 64 + row) * 4096 + j0 + p * 64 + c8,
                            VSM + (p * 64 + wave * 16 + j * 8) * 64);
                }
            __syncthreads();

            const int pp = g2;
            const int koff = j0 + pp * 64 - q0;
            if (koff > wl * 32 + 31) continue;     // fully masked for this wave

            // S^T = K·Q^T (C: col=query=l16, row=key=nt*16+quad*4+r)
            f32x4 st[2][4];
            for (int nt = 0; nt < 4; ++nt) {
                const __bf16* kr = KSM + (pp * 64 + nt * 16 + l16) * 64;
                bf16x8 kf0 = *(const bf16x8*)(kr + ((quad ^ swz) * 8));
                bf16x8 kf1 = *(const bf16x8*)(kr + (((4 + quad) ^ swz) * 8));
                for (int g = 0; g < 2; ++g) {
                    f32x4 zz = (f32x4){0.f, 0.f, 0.f, 0.f};
                    zz = mfma_k32(kf0, qf[g][0], zz);
                    zz = mfma_k32(kf1, qf[g][1], zz);
                    st[g][nt] = zz;
                }
            }

            // fixed-base softmax: p = exp2(st)
            bf16x4 pf[2][4];
            for (int g = 0; g < 2; ++g) {
                const int qb = wl * 32 + g * 16;
                if (koff + 63 <= qb) {
                    for (int nt = 0; nt < 4; ++nt)
                        for (int r = 0; r < 4; ++r) {
                            float p = fast_exp2(st[g][nt][r]);
                            lsum[g] += p;
                            pf[g][nt][r] = (bf16_t)p;
                        }
                } else {
                    const int qrow = qb + l16;
                    for (int nt = 0; nt < 4; ++nt)
                        for (int r = 0; r < 4; ++r) {
                            int key = nt * 16 + quad * 4 + r;
                            float p = (key + koff <= qrow) ? fast_exp2(st[g][nt][r]) : 0.f;
                            lsum[g] += p;
                            pf[g][nt][r] = (bf16_t)p;
                        }
                }
            }

            // O += P·V (P register-resident)
            for (int dt = 0; dt < 4; ++dt)
                for (int kt2 = 0; kt2 < 2; ++kt2) {
                    bf16x8 vf = *(const bf16x8*)&VSM[(pp * 64 + dt * 16 + l16) * 64 + (((2 * quad + kt2) ^ swz) * 8)];
                    bf16x4 vlo = {vf[0], vf[1], vf[2], vf[3]};
                    bf16x4 vhi = {vf[4], vf[5], vf[6], vf[7]};
                    for (int g = 0; g < 2; ++g) {
                        o[g][dt] = mfma_k16(pf[g][2 * kt2], vlo, o[g][dt]);
                        o[g][dt] = mfma_k16(pf[g][2 * kt2 + 1], vhi, o[g][dt]);
                    }
                }
        }

        // ---- combine K-parity partials within block, write leg partials ----
        __syncthreads();                    // all K/V LDS reads done
        if (g2 == 1) {
            for (int g = 0; g < 2; ++g) {
                float ls = lsum[g];
                ls += __shfl_xor(ls, 16);
                ls += __shfl_xor(ls, 32);
                const int qb = wl * 32 + g * 16;
                Lsc[qb + l16] = ls;
                for (int dt = 0; dt < 4; ++dt)
                    for (int r = 0; r < 4; ++r)
                        Osc[(qb + quad * 4 + r) * 65 + dt * 16 + l16] = o[g][dt][r];
            }
        }
        __syncthreads();
        if (g2 == 0) {
            for (int g = 0; g < 2; ++g) {
                float ls = lsum[g];
                ls += __shfl_xor(ls, 16);
                ls += __shfl_xor(ls, 32);
                const int qb = wl * 32 + g * 16;
                ls += Lsc[qb + l16];
                Lsc[qb + l16] = ls;         // total lsum for this z
                for (int dt = 0; dt < 4; ++dt)
                    for (int r = 0; r < 4; ++r) {
                        int idx = (qb + quad * 4 + r) * 65 + dt * 16 + l16;
                        Osc[idx] = o[g][dt][r] + Osc[idx];
                    }
            }
        }
        __syncthreads();
        // repack: contiguous bf16 partial rows [q][e] + fp32 lsum
        {
            const int q  = tid >> 2;
            const int e0 = (tid & 3) * 16;
            bf16x8 w0, w1;
            for (int i = 0; i < 8; ++i) {
                w0[i] = (bf16_t)Osc[q * 65 + e0 + i];
                w1[i] = (bf16_t)Osc[q * 65 + e0 + 8 + i];
            }
            size_t slot = ((size_t)(bh * 64 + qt)) * 4096 + q * 64 + e0;
            *(bf16x8*)&Op[slot]     = w0;
            *(bf16x8*)&Op[slot + 8] = w1;
            if (tid < 64) Lp[(bh * 64 + qt) * 64 + tid] = Lsc[tid];
        }
        // next leg's first __syncthreads() protects Osc/Lsc reuse
    }
}

// ---------------------------------------------------------------------------
extern "C" void kernel_launch(void* const* d_in, const int* in_sizes, int n_in,
                              void* d_out, int out_size, void* d_ws, size_t ws_size,
                              hipStream_t stream) {
    const float* q  = (const float*)d_in[0];
    const float* k  = (const float*)d_in[1];
    const float* v  = (const float*)d_in[2];
    const float* Wq = (const float*)d_in[3];
    const float* Wk = (const float*)d_in[4];
    const float* Wv = (const float*)d_in[5];
    const float* Wo = (const float*)d_in[6];
    float* out = (float*)d_out;

    bf16_t* ws = (bf16_t*)d_ws;
    const size_t R = (size_t)8192 * 512;   // 4.19M elems = 8.39 MB per region
    bf16_t* opart = ws + R;          // R1+R2: Opart z0/z1
    bf16_t* vh = ws + 3 * R;         // R3: V^T heads
    bf16_t* Wc = ws + 4 * R;         // +2 MB bf16 weights (Wq pre-scaled)
    float*  Lp = (float*)(ws + 4 * R + 1048576);  // +0.5 MB lsum partials
    bf16_t* qh = (bf16_t*)d_out;     // qh/kh in d_out, dead before final GEMM
    bf16_t* kh = (bf16_t*)d_out + R;

    cvt_W<<<dim3(512), dim3(256), 0, stream>>>(Wq, Wk, Wv, Wo, Wc);
    proj_fused<<<dim3(256, 1, 3), dim3(256), 0, stream>>>(q, k, v, Wc, qh, kh, vh);
    attn_kernel<<<dim3(1024), dim3(256), 0, stream>>>(qh, kh, vh, opart, Lp);
    gemm_final<<<dim3(256), dim3(256), 0, stream>>>(opart, Lp, Wc + 3 * 262144, out);
}